// Round 8
// baseline (807.088 us; speedup 1.0000x reference)
//
#include <hip/hip_runtime.h>
#include <hip/hip_bf16.h>
#include <stdint.h>

#define NN 50000
#define NE 1600000
#define BE 128

typedef __attribute__((ext_vector_type(8))) short short8;
typedef __attribute__((ext_vector_type(4))) float f32x4;

__device__ __forceinline__ unsigned short f2bf(float f) {
    unsigned int u = __float_as_uint(f);
    u += 0x7fff + ((u >> 16) & 1);   // round-nearest-even
    return (unsigned short)(u >> 16);
}

__device__ __forceinline__ unsigned int pk2bf(float lo, float hi) {
    __hip_bfloat162 b = __float22bfloat162_rn(float2{lo, hi});
    return *(unsigned int*)&b;
}

__device__ __forceinline__ float silu_f(float v) {
    return v * __builtin_amdgcn_rcpf(1.0f + __expf(-v));
}

// ws layout (bytes):
// [0, 98304)              bf16 weights: node_w1^T | coord_w1^T | node_w2^T
// [98304, 100352)         ew2^T bf16 [32][32]
// [100352, 6500352)       h_bf16 [50000][64]           (gated)
// [6500352, 7300352)      x4 float4 [50000]            (gated)
// [7300352, 7501056)      hist int[50000] (+pad)       (sort, gated)
// [7501056, 13901056)     src_s int[NE]
// [13901056, 20301056)    dst_s int[NE]
// [20301056, 26701056)    dist_s float[NE]
#define WS_EW2T_US   49152
#define WS_HB_B      100352
#define WS_XP_B      6500352
#define WS_HB_NEED   6500352
#define WS_XP_NEED   7300352
#define WS_HIST_B    7300352
#define WS_SRC_B     7501056
#define WS_DST_B     13901056
#define WS_DIST_B    20301056
#define WS_SORT_NEED 26701056

__global__ void prep_kernel(const float* __restrict__ nw1,
                            const float* __restrict__ cw1,
                            const float* __restrict__ nw2,
                            const float* __restrict__ ew2,
                            unsigned short* __restrict__ ws) {
    int i = blockIdx.x * 256 + threadIdx.x;
    if (i < 20480) {
        int n = i / 160, k = i % 160;
        ws[i] = f2bf(nw1[k * 128 + n]);
    } else if (i < 40960) {
        int j = i - 20480; int n = j / 160, k = j % 160;
        ws[i] = f2bf(cw1[k * 128 + n]);
    } else if (i < 49152) {
        int j = i - 40960; int o = j / 128, k = j % 128;
        ws[i] = f2bf(nw2[k * 64 + o]);
    } else if (i < 50176) {
        int j = i - 49152; int jo = j >> 5, k = j & 31;
        ws[i] = f2bf(ew2[k * 32 + jo]);
    }
}

// fused: out_h init + h->bf16 + x->float4 + out_x init
__global__ void fused_init(const float4* __restrict__ h4,
                           const float* __restrict__ x,
                           const float4* __restrict__ x4,
                           float4* __restrict__ out4,
                           unsigned short* __restrict__ hb,
                           float4* __restrict__ xp) {
    int i = blockIdx.x * 256 + threadIdx.x;
    if (i < 800000) {
        float4 v = h4[i];
        out4[i] = v;
        if (hb) {
            uint2 u;
            u.x = pk2bf(v.x, v.y);
            u.y = pk2bf(v.z, v.w);
            *(uint2*)&hb[i * 4] = u;
        }
    } else if (i < 850000) {
        int n = i - 800000;
        if (xp) xp[n] = float4{x[n * 3], x[n * 3 + 1], x[n * 3 + 2], 0.f};
    } else if (i < 887500) {
        int j = i - 850000;
        out4[800000 + j] = x4[j];
    }
}

// ---------------- counting-sort of edges by dst (materialized triples) ----------------
__global__ void zero_hist(int* __restrict__ hist) {
    int i = blockIdx.x * 256 + threadIdx.x;
    if (i < NN) hist[i] = 0;
}

__global__ void hist_kernel(const int* __restrict__ eidx, int* __restrict__ hist) {
    int e = blockIdx.x * 256 + threadIdx.x;
    if (e < NE) atomicAdd(&hist[eidx[NE + e]], 1);
}

__global__ __launch_bounds__(1024)
void scan_kernel(int* __restrict__ hist) {
    __shared__ int tmp[1024];
    __shared__ int carry;
    const int tid = threadIdx.x;
    if (tid == 0) carry = 0;
    __syncthreads();
    for (int base = 0; base < NN; base += 1024) {
        int v = (base + tid < NN) ? hist[base + tid] : 0;
        tmp[tid] = v;
        __syncthreads();
        #pragma unroll
        for (int off = 1; off < 1024; off <<= 1) {
            int t = (tid >= off) ? tmp[tid - off] : 0;
            __syncthreads();
            tmp[tid] += t;
            __syncthreads();
        }
        int excl = carry + tmp[tid] - v;
        if (base + tid < NN) hist[base + tid] = excl;
        __syncthreads();
        if (tid == 1023) carry += tmp[1023];
        __syncthreads();
    }
}

__global__ void scatter_kernel(const int* __restrict__ eidx,
                               const float* __restrict__ edist,
                               int* __restrict__ offs,
                               int* __restrict__ src_s,
                               int* __restrict__ dst_s,
                               float* __restrict__ dist_s) {
    int e = blockIdx.x * 256 + threadIdx.x;
    if (e < NE) {
        int d = eidx[NE + e];
        int p = atomicAdd(&offs[d], 1);
        src_s[p]  = eidx[e];
        dst_s[p]  = d;
        dist_s[p] = edist[e];
    }
}

#define MIS 168    // m_input row stride (ushorts); 336B = 21*16B
#define MAS 84     // macc fp32 row stride = MIS/2: row lrow (256B used) sits INSIDE mi row lrow (336B)

// ================= sorted-edge kernel: segmented reduce, ~7M atomic dwords =================
__global__ __launch_bounds__(256, 3)
void egnn_edge_sorted(const float* __restrict__ h,
                      const unsigned short* __restrict__ hb,
                      const float* __restrict__ x,
                      const float4* __restrict__ xp,
                      const int* __restrict__ src_s,
                      const int* __restrict__ dst_s,
                      const float* __restrict__ dist_s,
                      const float* __restrict__ node_b1,
                      const float* __restrict__ node_b2,
                      const float* __restrict__ coord_b1,
                      const float* __restrict__ coord_w2,
                      const float* __restrict__ ew1,
                      const float* __restrict__ eb1,
                      const float* __restrict__ eb2,
                      const unsigned short* __restrict__ ws,
                      float* __restrict__ out_h,
                      float* __restrict__ out_x) {
    // LDS: 43008 (mi; macc[128][84] fp32 aliases it exactly) + 512 + 512 + 1536 = 45568 -> 3 blocks/CU
    __shared__ unsigned short mi[BE * MIS];
    __shared__ int srcS[BE];
    __shared__ int dstS[BE];
    __shared__ float xacc[BE][3];

    const int tid  = threadIdx.x;
    const int w    = tid >> 6;
    const int lane = tid & 63;
    const int ln   = lane & 15;
    const int quad = lane >> 4;
    const int e0   = blockIdx.x * BE;

    if (tid < BE)      srcS[tid]      = src_s[e0 + tid];
    else               dstS[tid - BE] = dst_s[e0 + tid - BE];
    __syncthreads();

    // ---- stage cols 0..127: gather h[src], h[dst] (dst runs are L1-hot) ----
    if (hb) {
        const uint2* hb2 = (const uint2*)hb;
        const int g = tid >> 4, l16 = tid & 15;
        #pragma unroll
        for (int it = 0; it < 16; ++it) {
            int row = it * 16 + g;
            int e = row & 127;
            int node = (row < 128) ? srcS[e] : dstS[e];
            int cbase = (row < 128) ? 0 : 64;
            *(uint2*)&mi[e * MIS + cbase + l16 * 4] = hb2[node * 16 + l16];
        }
    } else {
        const float4* h4 = (const float4*)h;
        const int g = tid >> 4, l16 = tid & 15;
        #pragma unroll
        for (int it = 0; it < 16; ++it) {
            int row = it * 16 + g;
            int e = row & 127;
            int node = (row < 128) ? srcS[e] : dstS[e];
            int cbase = (row < 128) ? 0 : 64;
            float4 v = h4[node * 16 + l16];
            uint2 u;
            u.x = pk2bf(v.x, v.y);
            u.y = pk2bf(v.z, v.w);
            *(uint2*)&mi[e * MIS + cbase + l16 * 4] = u;
        }
    }
    // ---- stage cols 128..159: t[e][k] = silu(d*ew1[k]+eb1[k]) ----
    {
        int e = tid >> 1, half = tid & 1;
        float d = dist_s[e0 + e];
        float t[16];
        #pragma unroll
        for (int j = 0; j < 16; ++j) {
            int k = half * 16 + j;
            t[j] = silu_f(d * ew1[k] + eb1[k]);
        }
        uint4 u0, u1;
        u0.x = pk2bf(t[0], t[1]);   u0.y = pk2bf(t[2], t[3]);
        u0.z = pk2bf(t[4], t[5]);   u0.w = pk2bf(t[6], t[7]);
        u1.x = pk2bf(t[8], t[9]);   u1.y = pk2bf(t[10], t[11]);
        u1.z = pk2bf(t[12], t[13]); u1.w = pk2bf(t[14], t[15]);
        *(uint4*)&mi[e * MIS + 128 + half * 16]     = u0;
        *(uint4*)&mi[e * MIS + 128 + half * 16 + 8] = u1;
    }

    __syncthreads();   // staging complete; each wave now touches only its own 32 rows

    const int arow0 = (w * 32 + ln) * MIS;
    const int arow1 = (w * 32 + 16 + ln) * MIS;
    const int koff  = quad * 8;
    const f32x4 zero = {0.f, 0.f, 0.f, 0.f};

    // ---- edge_attr = tmat @ ew2 + eb2 via MFMA, in place ----
    {
        const unsigned short* e2T = ws + WS_EW2T_US;
        short8 ta0 = *(const short8*)&mi[arow0 + 128 + koff];
        short8 ta1 = *(const short8*)&mi[arow1 + 128 + koff];
        f32x4 ea[2][2];
        ea[0][0] = zero; ea[0][1] = zero; ea[1][0] = zero; ea[1][1] = zero;
        #pragma unroll
        for (int nt = 0; nt < 2; ++nt) {
            short8 b = *(const short8*)(e2T + (nt * 16 + ln) * 32 + koff);
            ea[0][nt] = __builtin_amdgcn_mfma_f32_16x16x32_bf16(ta0, b, ea[0][nt], 0, 0, 0);
            ea[1][nt] = __builtin_amdgcn_mfma_f32_16x16x32_bf16(ta1, b, ea[1][nt], 0, 0, 0);
        }
        #pragma unroll
        for (int nt = 0; nt < 2; ++nt) {
            int col = nt * 16 + ln;
            float bv = eb2[col];
            #pragma unroll
            for (int rt = 0; rt < 2; ++rt) {
                #pragma unroll
                for (int r = 0; r < 4; ++r)
                    mi[(w * 32 + rt * 16 + quad * 4 + r) * MIS + 128 + col] =
                        f2bf(ea[rt][nt][r] + bv);
            }
        }
    }

    // ---- A fragments ----
    short8 aA[5], aB[5];
    #pragma unroll
    for (int kc = 0; kc < 5; ++kc) {
        aA[kc] = *(const short8*)&mi[arow0 + kc * 32 + koff];
        aB[kc] = *(const short8*)&mi[arow1 + kc * 32 + koff];
    }

    const int wvoff = ln * 160 + koff;

    // ---- GEMM1-coord ----
    f32x4 accC[2][8];
    #pragma unroll
    for (int a = 0; a < 2; ++a)
        #pragma unroll
        for (int b = 0; b < 8; ++b) accC[a][b] = zero;
    {
        const unsigned short* wsrc = ws + 20480;
        #pragma unroll
        for (int half = 0; half < 2; ++half) {
            #pragma unroll
            for (int kc = 0; kc < 5; ++kc) {
                #pragma unroll
                for (int nt = 0; nt < 4; ++nt) {
                    short8 b = *(const short8*)(wsrc + half * 10240 + nt * 2560
                                                + kc * 32 + wvoff);
                    const int nn = half * 4 + nt;
                    accC[0][nn] = __builtin_amdgcn_mfma_f32_16x16x32_bf16(aA[kc], b, accC[0][nn], 0, 0, 0);
                    accC[1][nn] = __builtin_amdgcn_mfma_f32_16x16x32_bf16(aB[kc], b, accC[1][nn], 0, 0, 0);
                }
            }
        }
    }

    // ---- coord epilogue -> xacc (no atomics here) ----
    {
        float cw[2][4];
        #pragma unroll
        for (int mt = 0; mt < 2; ++mt)
            #pragma unroll
            for (int r = 0; r < 4; ++r) cw[mt][r] = 0.f;
        #pragma unroll
        for (int nt = 0; nt < 8; ++nt) {
            int col = nt * 16 + ln;
            float b1v = coord_b1[col];
            float w2v = coord_w2[col];
            #pragma unroll
            for (int mt = 0; mt < 2; ++mt)
                #pragma unroll
                for (int r = 0; r < 4; ++r)
                    cw[mt][r] += silu_f(accC[mt][nt][r] + b1v) * w2v;
        }
        #pragma unroll
        for (int off = 1; off < 16; off <<= 1) {
            #pragma unroll
            for (int mt = 0; mt < 2; ++mt)
                #pragma unroll
                for (int r = 0; r < 4; ++r)
                    cw[mt][r] += __shfl_xor(cw[mt][r], off, 64);
        }
        if (ln < 8) {
            const int smt = ln >> 2, sr = ln & 3;
            float cwsel = 0.f;
            #pragma unroll
            for (int mt = 0; mt < 2; ++mt)
                #pragma unroll
                for (int r = 0; r < 4; ++r)
                    cwsel = (mt == smt && r == sr) ? cw[mt][r] : cwsel;
            int lrow = w * 32 + smt * 16 + quad * 4 + sr;
            int s = srcS[lrow], dn = dstS[lrow];
            float dx, dy, dz;
            if (xp) {
                float4 xs = xp[s], xd = xp[dn];
                dx = xs.x - xd.x; dy = xs.y - xd.y; dz = xs.z - xd.z;
            } else {
                dx = x[s * 3]     - x[dn * 3];
                dy = x[s * 3 + 1] - x[dn * 3 + 1];
                dz = x[s * 3 + 2] - x[dn * 3 + 2];
            }
            float len = fmaxf(sqrtf(dx * dx + dy * dy + dz * dz), 1e-8f);
            float k = cwsel * __builtin_amdgcn_rcpf(len);
            xacc[lrow][0] = k * dx;
            xacc[lrow][1] = k * dy;
            xacc[lrow][2] = k * dz;
        }
    }

    // ---- GEMM1-node ----
    f32x4 accN[2][8];
    #pragma unroll
    for (int a = 0; a < 2; ++a)
        #pragma unroll
        for (int b = 0; b < 8; ++b) accN[a][b] = zero;
    {
        const unsigned short* wsrc = ws;
        #pragma unroll
        for (int half = 0; half < 2; ++half) {
            #pragma unroll
            for (int kc = 0; kc < 5; ++kc) {
                #pragma unroll
                for (int nt = 0; nt < 4; ++nt) {
                    short8 b = *(const short8*)(wsrc + half * 10240 + nt * 2560
                                                + kc * 32 + wvoff);
                    const int nn = half * 4 + nt;
                    accN[0][nn] = __builtin_amdgcn_mfma_f32_16x16x32_bf16(aA[kc], b, accN[0][nn], 0, 0, 0);
                    accN[1][nn] = __builtin_amdgcn_mfma_f32_16x16x32_bf16(aB[kc], b, accN[1][nn], 0, 0, 0);
                }
            }
        }
    }

    // ---- hidden = silu(accN + b1) -> bf16, own rows ----
    #pragma unroll
    for (int mt = 0; mt < 2; ++mt) {
        const int rowb = (w * 32 + mt * 16 + quad * 4) * MIS;
        #pragma unroll
        for (int nt = 0; nt < 8; ++nt) {
            int col = nt * 16 + ln;
            float b1v = node_b1[col];
            #pragma unroll
            for (int r = 0; r < 4; ++r)
                mi[rowb + r * MIS + col] = f2bf(silu_f(accN[mt][nt][r] + b1v));
        }
    }

    // ---- GEMM2-node ----
    f32x4 acc2[2][4];
    #pragma unroll
    for (int a = 0; a < 2; ++a)
        #pragma unroll
        for (int b = 0; b < 4; ++b) acc2[a][b] = zero;
    const unsigned short* nw2T = ws + 40960;
    #pragma unroll
    for (int kc = 0; kc < 4; ++kc) {
        short8 a0 = *(const short8*)&mi[arow0 + kc * 32 + koff];
        short8 a1 = *(const short8*)&mi[arow1 + kc * 32 + koff];
        #pragma unroll
        for (int nt = 0; nt < 4; ++nt) {
            short8 b = *(const short8*)(nw2T + (nt * 16 + ln) * 128 + kc * 32 + koff);
            acc2[0][nt] = __builtin_amdgcn_mfma_f32_16x16x32_bf16(a0, b, acc2[0][nt], 0, 0, 0);
            acc2[1][nt] = __builtin_amdgcn_mfma_f32_16x16x32_bf16(a1, b, acc2[1][nt], 0, 0, 0);
        }
    }

    // ---- m+b2 rows -> LDS fp32 ----
    // RACE FIX (round-7 NaN post-mortem): all waves' GEMM2 LDS reads must complete
    // before ANY wave's fp32 overwrite of mi. MAS=84 additionally keeps row lrow's
    // fp32 bytes inside mi row lrow, so writes stay in own-wave rows by construction.
    __syncthreads();
    float* macc = (float*)mi;   // [128][MAS]
    #pragma unroll
    for (int mt = 0; mt < 2; ++mt) {
        #pragma unroll
        for (int r = 0; r < 4; ++r) {
            int lrow = w * 32 + mt * 16 + quad * 4 + r;
            #pragma unroll
            for (int nt = 0; nt < 4; ++nt) {
                int col = nt * 16 + ln;
                macc[lrow * MAS + col] = acc2[mt][nt][r] + node_b2[col];
            }
        }
    }
    __syncthreads();   // macc + xacc visible to all

    // ---- segmented reduce: thread = (col, row-quarter); wave-uniform branches ----
    {
        const int col = tid & 63;
        const int q   = tid >> 6;
        const int r0  = q * 32;
        float sum = 0.f;
        int prev = dstS[r0];
        for (int r = r0; r < r0 + 32; ++r) {
            int d = dstS[r];
            if (d != prev) {
                atomicAdd(out_h + (size_t)prev * 64 + col, sum);
                sum = 0.f; prev = d;
            }
            sum += macc[r * MAS + col];
        }
        atomicAdd(out_h + (size_t)prev * 64 + col, sum);

        if (col < 3) {
            float xs = 0.f;
            int pv = dstS[r0];
            for (int r = r0; r < r0 + 32; ++r) {
                int d = dstS[r];
                if (d != pv) {
                    atomicAdd(out_x + pv * 3 + col, xs);
                    xs = 0.f; pv = d;
                }
                xs += xacc[r][col];
            }
            atomicAdd(out_x + pv * 3 + col, xs);
        }
    }
}

// ================= fallback: round-5 kernel (per-edge atomics), verbatim =================
__global__ __launch_bounds__(256, 3)
void egnn_edge_kernel(const float* __restrict__ h,
                      const unsigned short* __restrict__ hb,
                      const float* __restrict__ x,
                      const float4* __restrict__ xp,
                      const int* __restrict__ eidx,
                      const float* __restrict__ edist,
                      const float* __restrict__ node_b1,
                      const float* __restrict__ node_b2,
                      const float* __restrict__ coord_b1,
                      const float* __restrict__ coord_w2,
                      const float* __restrict__ ew1,
                      const float* __restrict__ eb1,
                      const float* __restrict__ eb2,
                      const unsigned short* __restrict__ ws,
                      float* __restrict__ out_h,
                      float* __restrict__ out_x) {
    __shared__ unsigned short mi[BE * MIS];
    __shared__ int srcS[BE];
    __shared__ int dstS[BE];

    const int tid  = threadIdx.x;
    const int w    = tid >> 6;
    const int lane = tid & 63;
    const int ln   = lane & 15;
    const int quad = lane >> 4;
    const int e0   = blockIdx.x * BE;

    if (tid < BE)      srcS[tid]       = eidx[e0 + tid];
    else               dstS[tid - BE]  = eidx[NE + e0 + tid - BE];
    __syncthreads();

    if (hb) {
        const uint2* hb2 = (const uint2*)hb;
        const int g = tid >> 4, l16 = tid & 15;
        #pragma unroll
        for (int it = 0; it < 16; ++it) {
            int row = it * 16 + g;
            int e = row & 127;
            int node = (row < 128) ? srcS[e] : dstS[e];
            int cbase = (row < 128) ? 0 : 64;
            *(uint2*)&mi[e * MIS + cbase + l16 * 4] = hb2[node * 16 + l16];
        }
    } else {
        const float4* h4 = (const float4*)h;
        const int g = tid >> 4, l16 = tid & 15;
        #pragma unroll
        for (int it = 0; it < 16; ++it) {
            int row = it * 16 + g;
            int e = row & 127;
            int node = (row < 128) ? srcS[e] : dstS[e];
            int cbase = (row < 128) ? 0 : 64;
            float4 v = h4[node * 16 + l16];
            uint2 u;
            u.x = pk2bf(v.x, v.y);
            u.y = pk2bf(v.z, v.w);
            *(uint2*)&mi[e * MIS + cbase + l16 * 4] = u;
        }
    }
    {
        int e = tid >> 1, half = tid & 1;
        float d = edist[e0 + e];
        float t[16];
        #pragma unroll
        for (int j = 0; j < 16; ++j) {
            int k = half * 16 + j;
            t[j] = silu_f(d * ew1[k] + eb1[k]);
        }
        uint4 u0, u1;
        u0.x = pk2bf(t[0], t[1]);   u0.y = pk2bf(t[2], t[3]);
        u0.z = pk2bf(t[4], t[5]);   u0.w = pk2bf(t[6], t[7]);
        u1.x = pk2bf(t[8], t[9]);   u1.y = pk2bf(t[10], t[11]);
        u1.z = pk2bf(t[12], t[13]); u1.w = pk2bf(t[14], t[15]);
        *(uint4*)&mi[e * MIS + 128 + half * 16]     = u0;
        *(uint4*)&mi[e * MIS + 128 + half * 16 + 8] = u1;
    }

    __syncthreads();

    const int arow0 = (w * 32 + ln) * MIS;
    const int arow1 = (w * 32 + 16 + ln) * MIS;
    const int koff  = quad * 8;
    const f32x4 zero = {0.f, 0.f, 0.f, 0.f};

    {
        const unsigned short* e2T = ws + WS_EW2T_US;
        short8 ta0 = *(const short8*)&mi[arow0 + 128 + koff];
        short8 ta1 = *(const short8*)&mi[arow1 + 128 + koff];
        f32x4 ea[2][2];
        ea[0][0] = zero; ea[0][1] = zero; ea[1][0] = zero; ea[1][1] = zero;
        #pragma unroll
        for (int nt = 0; nt < 2; ++nt) {
            short8 b = *(const short8*)(e2T + (nt * 16 + ln) * 32 + koff);
            ea[0][nt] = __builtin_amdgcn_mfma_f32_16x16x32_bf16(ta0, b, ea[0][nt], 0, 0, 0);
            ea[1][nt] = __builtin_amdgcn_mfma_f32_16x16x32_bf16(ta1, b, ea[1][nt], 0, 0, 0);
        }
        #pragma unroll
        for (int nt = 0; nt < 2; ++nt) {
            int col = nt * 16 + ln;
            float bv = eb2[col];
            #pragma unroll
            for (int rt = 0; rt < 2; ++rt) {
                #pragma unroll
                for (int r = 0; r < 4; ++r)
                    mi[(w * 32 + rt * 16 + quad * 4 + r) * MIS + 128 + col] =
                        f2bf(ea[rt][nt][r] + bv);
            }
        }
    }

    short8 aA[5], aB[5];
    #pragma unroll
    for (int kc = 0; kc < 5; ++kc) {
        aA[kc] = *(const short8*)&mi[arow0 + kc * 32 + koff];
        aB[kc] = *(const short8*)&mi[arow1 + kc * 32 + koff];
    }

    const int wvoff = ln * 160 + koff;

    f32x4 accC[2][8];
    #pragma unroll
    for (int a = 0; a < 2; ++a)
        #pragma unroll
        for (int b = 0; b < 8; ++b) accC[a][b] = zero;
    {
        const unsigned short* wsrc = ws + 20480;
        #pragma unroll
        for (int half = 0; half < 2; ++half) {
            #pragma unroll
            for (int kc = 0; kc < 5; ++kc) {
                #pragma unroll
                for (int nt = 0; nt < 4; ++nt) {
                    short8 b = *(const short8*)(wsrc + half * 10240 + nt * 2560
                                                + kc * 32 + wvoff);
                    const int nn = half * 4 + nt;
                    accC[0][nn] = __builtin_amdgcn_mfma_f32_16x16x32_bf16(aA[kc], b, accC[0][nn], 0, 0, 0);
                    accC[1][nn] = __builtin_amdgcn_mfma_f32_16x16x32_bf16(aB[kc], b, accC[1][nn], 0, 0, 0);
                }
            }
        }
    }

    {
        float cw[2][4];
        #pragma unroll
        for (int mt = 0; mt < 2; ++mt)
            #pragma unroll
            for (int r = 0; r < 4; ++r) cw[mt][r] = 0.f;
        #pragma unroll
        for (int nt = 0; nt < 8; ++nt) {
            int col = nt * 16 + ln;
            float b1v = coord_b1[col];
            float w2v = coord_w2[col];
            #pragma unroll
            for (int mt = 0; mt < 2; ++mt)
                #pragma unroll
                for (int r = 0; r < 4; ++r)
                    cw[mt][r] += silu_f(accC[mt][nt][r] + b1v) * w2v;
        }
        #pragma unroll
        for (int off = 1; off < 16; off <<= 1) {
            #pragma unroll
            for (int mt = 0; mt < 2; ++mt)
                #pragma unroll
                for (int r = 0; r < 4; ++r)
                    cw[mt][r] += __shfl_xor(cw[mt][r], off, 64);
        }
        if (ln < 8) {
            const int smt = ln >> 2, sr = ln & 3;
            float cwsel = 0.f;
            #pragma unroll
            for (int mt = 0; mt < 2; ++mt)
                #pragma unroll
                for (int r = 0; r < 4; ++r)
                    cwsel = (mt == smt && r == sr) ? cw[mt][r] : cwsel;
            int lrow = w * 32 + smt * 16 + quad * 4 + sr;
            int s = srcS[lrow], dn = dstS[lrow];
            float dx, dy, dz;
            if (xp) {
                float4 xs = xp[s], xd = xp[dn];
                dx = xs.x - xd.x; dy = xs.y - xd.y; dz = xs.z - xd.z;
            } else {
                dx = x[s * 3]     - x[dn * 3];
                dy = x[s * 3 + 1] - x[dn * 3 + 1];
                dz = x[s * 3 + 2] - x[dn * 3 + 2];
            }
            float len = fmaxf(sqrtf(dx * dx + dy * dy + dz * dz), 1e-8f);
            float k = cwsel * __builtin_amdgcn_rcpf(len);
            atomicAdd(out_x + dn * 3,     k * dx);
            atomicAdd(out_x + dn * 3 + 1, k * dy);
            atomicAdd(out_x + dn * 3 + 2, k * dz);
        }
    }

    f32x4 accN[2][8];
    #pragma unroll
    for (int a = 0; a < 2; ++a)
        #pragma unroll
        for (int b = 0; b < 8; ++b) accN[a][b] = zero;
    {
        const unsigned short* wsrc = ws;
        #pragma unroll
        for (int half = 0; half < 2; ++half) {
            #pragma unroll
            for (int kc = 0; kc < 5; ++kc) {
                #pragma unroll
                for (int nt = 0; nt < 4; ++nt) {
                    short8 b = *(const short8*)(wsrc + half * 10240 + nt * 2560
                                                + kc * 32 + wvoff);
                    const int nn = half * 4 + nt;
                    accN[0][nn] = __builtin_amdgcn_mfma_f32_16x16x32_bf16(aA[kc], b, accN[0][nn], 0, 0, 0);
                    accN[1][nn] = __builtin_amdgcn_mfma_f32_16x16x32_bf16(aB[kc], b, accN[1][nn], 0, 0, 0);
                }
            }
        }
    }

    #pragma unroll
    for (int mt = 0; mt < 2; ++mt) {
        const int rowb = (w * 32 + mt * 16 + quad * 4) * MIS;
        #pragma unroll
        for (int nt = 0; nt < 8; ++nt) {
            int col = nt * 16 + ln;
            float b1v = node_b1[col];
            #pragma unroll
            for (int r = 0; r < 4; ++r)
                mi[rowb + r * MIS + col] = f2bf(silu_f(accN[mt][nt][r] + b1v));
        }
    }

    f32x4 acc2[2][4];
    #pragma unroll
    for (int a = 0; a < 2; ++a)
        #pragma unroll
        for (int b = 0; b < 4; ++b) acc2[a][b] = zero;
    const unsigned short* nw2T = ws + 40960;
    #pragma unroll
    for (int kc = 0; kc < 4; ++kc) {
        short8 a0 = *(const short8*)&mi[arow0 + kc * 32 + koff];
        short8 a1 = *(const short8*)&mi[arow1 + kc * 32 + koff];
        #pragma unroll
        for (int nt = 0; nt < 4; ++nt) {
            short8 b = *(const short8*)(nw2T + (nt * 16 + ln) * 128 + kc * 32 + koff);
            acc2[0][nt] = __builtin_amdgcn_mfma_f32_16x16x32_bf16(a0, b, acc2[0][nt], 0, 0, 0);
            acc2[1][nt] = __builtin_amdgcn_mfma_f32_16x16x32_bf16(a1, b, acc2[1][nt], 0, 0, 0);
        }
    }
    #pragma unroll
    for (int mt = 0; mt < 2; ++mt) {
        #pragma unroll
        for (int r = 0; r < 4; ++r) {
            int lrow = w * 32 + mt * 16 + quad * 4 + r;
            int dn = dstS[lrow];
            float* outrow = out_h + (size_t)dn * 64;
            #pragma unroll
            for (int nt = 0; nt < 4; ++nt) {
                int col = nt * 16 + ln;
                atomicAdd(outrow + col, acc2[mt][nt][r] + node_b2[col]);
            }
        }
    }
}

extern "C" void kernel_launch(void* const* d_in, const int* in_sizes, int n_in,
                              void* d_out, int out_size, void* d_ws, size_t ws_size,
                              hipStream_t stream) {
    const float* h    = (const float*)d_in[0];
    const float* x    = (const float*)d_in[1];
    const int*   eidx = (const int*)d_in[2];
    const float* edist= (const float*)d_in[3];
    const float* nw1  = (const float*)d_in[4];
    const float* nb1  = (const float*)d_in[5];
    const float* nw2  = (const float*)d_in[6];
    const float* nb2  = (const float*)d_in[7];
    const float* cw1  = (const float*)d_in[8];
    const float* cb1  = (const float*)d_in[9];
    const float* cw2  = (const float*)d_in[10];
    const float* ew1  = (const float*)d_in[11];
    const float* eb1  = (const float*)d_in[12];
    const float* ew2  = (const float*)d_in[13];
    const float* eb2  = (const float*)d_in[14];
    float* out = (float*)d_out;
    unsigned short* ws = (unsigned short*)d_ws;

    unsigned short* hb = nullptr;
    float4* xp = nullptr;
    if (ws_size >= (size_t)WS_HB_NEED) hb = (unsigned short*)((char*)d_ws + WS_HB_B);
    if (ws_size >= (size_t)WS_XP_NEED) xp = (float4*)((char*)d_ws + WS_XP_B);

    prep_kernel<<<196, 256, 0, stream>>>(nw1, cw1, nw2, ew2, ws);
    fused_init<<<3468, 256, 0, stream>>>((const float4*)h, x, (const float4*)x,
                                         (float4*)out, hb, xp);

    if (ws_size >= (size_t)WS_SORT_NEED) {
        int*   hist   = (int*)((char*)d_ws + WS_HIST_B);
        int*   src_s  = (int*)((char*)d_ws + WS_SRC_B);
        int*   dst_s  = (int*)((char*)d_ws + WS_DST_B);
        float* dist_s = (float*)((char*)d_ws + WS_DIST_B);
        zero_hist<<<196, 256, 0, stream>>>(hist);
        hist_kernel<<<NE / 256, 256, 0, stream>>>(eidx, hist);
        scan_kernel<<<1, 1024, 0, stream>>>(hist);
        scatter_kernel<<<NE / 256, 256, 0, stream>>>(eidx, edist, hist,
                                                     src_s, dst_s, dist_s);
        egnn_edge_sorted<<<NE / BE, 256, 0, stream>>>(h, hb, x, xp,
                                                      src_s, dst_s, dist_s,
                                                      nb1, nb2, cb1, cw2,
                                                      ew1, eb1, eb2,
                                                      ws, out, out + 3200000);
    } else {
        egnn_edge_kernel<<<NE / BE, 256, 0, stream>>>(h, hb, x, xp, eidx, edist,
                                                      nb1, nb2, cb1, cw2,
                                                      ew1, eb1, eb2,
                                                      ws, out, out + 3200000);
    }
}

// Round 9
// 718.222 us; speedup vs baseline: 1.1237x; 1.1237x over previous
//
#include <hip/hip_runtime.h>
#include <hip/hip_bf16.h>
#include <stdint.h>

#define NN 50000
#define NE 1600000
#define BE 128

typedef __attribute__((ext_vector_type(8))) short short8;
typedef __attribute__((ext_vector_type(4))) float f32x4;

__device__ __forceinline__ unsigned short f2bf(float f) {
    unsigned int u = __float_as_uint(f);
    u += 0x7fff + ((u >> 16) & 1);   // round-nearest-even
    return (unsigned short)(u >> 16);
}

__device__ __forceinline__ unsigned int pk2bf(float lo, float hi) {
    __hip_bfloat162 b = __float22bfloat162_rn(float2{lo, hi});
    return *(unsigned int*)&b;
}

__device__ __forceinline__ float silu_f(float v) {
    return v * __builtin_amdgcn_rcpf(1.0f + __expf(-v));
}

// ws layout (bytes):
// [0, 98304)              bf16 weights: node_w1^T | coord_w1^T | node_w2^T
// [98304, 100352)         ew2^T bf16 [32][32]
// [100352, 6500352)       h_bf16 [50000][64]           (gated)
// [6500352, 7300352)      x4 float4 [50000]            (gated)
// [7300352, 7501056)      hist int[50176]: [0,50000) counters, [50000,50049) chunk sums
// [7501056, 13901056)     src_s int[NE]
// [13901056, 20301056)    dst_s int[NE]
// [20301056, 26701056)    dist_s float[NE]
#define WS_EW2T_US   49152
#define WS_HB_B      100352
#define WS_XP_B      6500352
#define WS_HB_NEED   6500352
#define WS_XP_NEED   7300352
#define WS_HIST_B    7300352
#define WS_SRC_B     7501056
#define WS_DST_B     13901056
#define WS_DIST_B    20301056
#define WS_SORT_NEED 26701056

__global__ void prep_kernel(const float* __restrict__ nw1,
                            const float* __restrict__ cw1,
                            const float* __restrict__ nw2,
                            const float* __restrict__ ew2,
                            unsigned short* __restrict__ ws) {
    int i = blockIdx.x * 256 + threadIdx.x;
    if (i < 20480) {
        int n = i / 160, k = i % 160;
        ws[i] = f2bf(nw1[k * 128 + n]);
    } else if (i < 40960) {
        int j = i - 20480; int n = j / 160, k = j % 160;
        ws[i] = f2bf(cw1[k * 128 + n]);
    } else if (i < 49152) {
        int j = i - 40960; int o = j / 128, k = j % 128;
        ws[i] = f2bf(nw2[k * 64 + o]);
    } else if (i < 50176) {
        int j = i - 49152; int jo = j >> 5, k = j & 31;
        ws[i] = f2bf(ew2[k * 32 + jo]);
    }
}

// fused: out_h init + h->bf16 + x->float4 + out_x init
__global__ void fused_init(const float4* __restrict__ h4,
                           const float* __restrict__ x,
                           const float4* __restrict__ x4,
                           float4* __restrict__ out4,
                           unsigned short* __restrict__ hb,
                           float4* __restrict__ xp) {
    int i = blockIdx.x * 256 + threadIdx.x;
    if (i < 800000) {
        float4 v = h4[i];
        out4[i] = v;
        if (hb) {
            uint2 u;
            u.x = pk2bf(v.x, v.y);
            u.y = pk2bf(v.z, v.w);
            *(uint2*)&hb[i * 4] = u;
        }
    } else if (i < 850000) {
        int n = i - 800000;
        if (xp) xp[n] = float4{x[n * 3], x[n * 3 + 1], x[n * 3 + 2], 0.f};
    } else if (i < 887500) {
        int j = i - 850000;
        out4[800000 + j] = x4[j];
    }
}

// ---------------- counting-sort of edges by dst (materialized triples) ----------------
__global__ void zero_hist(int* __restrict__ hist) {
    int i = blockIdx.x * 256 + threadIdx.x;
    if (i < NN) hist[i] = 0;
}

__global__ void hist_kernel(const int* __restrict__ eidx, int* __restrict__ hist) {
    int e = blockIdx.x * 256 + threadIdx.x;
    if (e < NE) atomicAdd(&hist[eidx[NE + e]], 1);
}

// hierarchical exclusive scan over hist[0..NN): 49 chunks x 1024
// (replaces the single-block ~200us scan; ~15us total)
__global__ __launch_bounds__(1024)
void scan_part(int* __restrict__ hist, int* __restrict__ sums) {
    __shared__ int tmp[1024];
    const int b = blockIdx.x, t = threadIdx.x;
    const int i = b * 1024 + t;
    int v = (i < NN) ? hist[i] : 0;
    tmp[t] = v;
    __syncthreads();
    #pragma unroll
    for (int off = 1; off < 1024; off <<= 1) {
        int u = (t >= off) ? tmp[t - off] : 0;
        __syncthreads();
        tmp[t] += u;
        __syncthreads();
    }
    if (i < NN) hist[i] = tmp[t] - v;       // exclusive within chunk
    if (t == 1023) sums[b] = tmp[1023];     // chunk total
}

__global__ void scan_sums(int* __restrict__ sums) {   // 1 block, 64 threads, 49 values
    const int t = threadIdx.x;
    int v = (t < 49) ? sums[t] : 0;
    int acc = v;
    #pragma unroll
    for (int off = 1; off < 64; off <<= 1) {
        int u = __shfl_up(acc, off, 64);
        if (t >= off) acc += u;
    }
    if (t < 49) sums[t] = acc - v;          // exclusive chunk offsets
}

__global__ __launch_bounds__(1024)
void scan_add(int* __restrict__ hist, const int* __restrict__ sums) {
    const int b = blockIdx.x, t = threadIdx.x;
    const int i = b * 1024 + t;
    if (i < NN) hist[i] += sums[b];
}

__global__ void scatter_kernel(const int* __restrict__ eidx,
                               const float* __restrict__ edist,
                               int* __restrict__ offs,
                               int* __restrict__ src_s,
                               int* __restrict__ dst_s,
                               float* __restrict__ dist_s) {
    int e = blockIdx.x * 256 + threadIdx.x;
    if (e < NE) {
        int d = eidx[NE + e];
        int p = atomicAdd(&offs[d], 1);
        src_s[p]  = eidx[e];
        dst_s[p]  = d;
        dist_s[p] = edist[e];
    }
}

#define MIS 168    // m_input row stride (ushorts); 336B = 21*16B
#define MAS 84     // macc fp32 row stride = MIS/2: row lrow (256B used) sits INSIDE mi row lrow (336B)

// ================= sorted-edge kernel: segmented reduce, ~7M atomic dwords =================
__global__ __launch_bounds__(256, 3)
void egnn_edge_sorted(const float* __restrict__ h,
                      const unsigned short* __restrict__ hb,
                      const float* __restrict__ x,
                      const float4* __restrict__ xp,
                      const int* __restrict__ src_s,
                      const int* __restrict__ dst_s,
                      const float* __restrict__ dist_s,
                      const float* __restrict__ node_b1,
                      const float* __restrict__ node_b2,
                      const float* __restrict__ coord_b1,
                      const float* __restrict__ coord_w2,
                      const float* __restrict__ ew1,
                      const float* __restrict__ eb1,
                      const float* __restrict__ eb2,
                      const unsigned short* __restrict__ ws,
                      float* __restrict__ out_h,
                      float* __restrict__ out_x) {
    // LDS: 43008 (mi; macc[128][84] fp32 aliases it exactly) + 512 + 512 + 1536 = 45568 -> 3 blocks/CU
    __shared__ unsigned short mi[BE * MIS];
    __shared__ int srcS[BE];
    __shared__ int dstS[BE];
    __shared__ float xacc[BE][3];

    const int tid  = threadIdx.x;
    const int w    = tid >> 6;
    const int lane = tid & 63;
    const int ln   = lane & 15;
    const int quad = lane >> 4;
    const int e0   = blockIdx.x * BE;

    if (tid < BE)      srcS[tid]      = src_s[e0 + tid];
    else               dstS[tid - BE] = dst_s[e0 + tid - BE];
    __syncthreads();

    // ---- stage cols 0..127: gather h[src], h[dst] (dst runs are L1-hot) ----
    if (hb) {
        const uint2* hb2 = (const uint2*)hb;
        const int g = tid >> 4, l16 = tid & 15;
        #pragma unroll
        for (int it = 0; it < 16; ++it) {
            int row = it * 16 + g;
            int e = row & 127;
            int node = (row < 128) ? srcS[e] : dstS[e];
            int cbase = (row < 128) ? 0 : 64;
            *(uint2*)&mi[e * MIS + cbase + l16 * 4] = hb2[node * 16 + l16];
        }
    } else {
        const float4* h4 = (const float4*)h;
        const int g = tid >> 4, l16 = tid & 15;
        #pragma unroll
        for (int it = 0; it < 16; ++it) {
            int row = it * 16 + g;
            int e = row & 127;
            int node = (row < 128) ? srcS[e] : dstS[e];
            int cbase = (row < 128) ? 0 : 64;
            float4 v = h4[node * 16 + l16];
            uint2 u;
            u.x = pk2bf(v.x, v.y);
            u.y = pk2bf(v.z, v.w);
            *(uint2*)&mi[e * MIS + cbase + l16 * 4] = u;
        }
    }
    // ---- stage cols 128..159: t[e][k] = silu(d*ew1[k]+eb1[k]) ----
    {
        int e = tid >> 1, half = tid & 1;
        float d = dist_s[e0 + e];
        float t[16];
        #pragma unroll
        for (int j = 0; j < 16; ++j) {
            int k = half * 16 + j;
            t[j] = silu_f(d * ew1[k] + eb1[k]);
        }
        uint4 u0, u1;
        u0.x = pk2bf(t[0], t[1]);   u0.y = pk2bf(t[2], t[3]);
        u0.z = pk2bf(t[4], t[5]);   u0.w = pk2bf(t[6], t[7]);
        u1.x = pk2bf(t[8], t[9]);   u1.y = pk2bf(t[10], t[11]);
        u1.z = pk2bf(t[12], t[13]); u1.w = pk2bf(t[14], t[15]);
        *(uint4*)&mi[e * MIS + 128 + half * 16]     = u0;
        *(uint4*)&mi[e * MIS + 128 + half * 16 + 8] = u1;
    }

    __syncthreads();   // staging complete; each wave now touches only its own 32 rows

    const int arow0 = (w * 32 + ln) * MIS;
    const int arow1 = (w * 32 + 16 + ln) * MIS;
    const int koff  = quad * 8;
    const f32x4 zero = {0.f, 0.f, 0.f, 0.f};

    // ---- edge_attr = tmat @ ew2 + eb2 via MFMA, in place ----
    {
        const unsigned short* e2T = ws + WS_EW2T_US;
        short8 ta0 = *(const short8*)&mi[arow0 + 128 + koff];
        short8 ta1 = *(const short8*)&mi[arow1 + 128 + koff];
        f32x4 ea[2][2];
        ea[0][0] = zero; ea[0][1] = zero; ea[1][0] = zero; ea[1][1] = zero;
        #pragma unroll
        for (int nt = 0; nt < 2; ++nt) {
            short8 b = *(const short8*)(e2T + (nt * 16 + ln) * 32 + koff);
            ea[0][nt] = __builtin_amdgcn_mfma_f32_16x16x32_bf16(ta0, b, ea[0][nt], 0, 0, 0);
            ea[1][nt] = __builtin_amdgcn_mfma_f32_16x16x32_bf16(ta1, b, ea[1][nt], 0, 0, 0);
        }
        #pragma unroll
        for (int nt = 0; nt < 2; ++nt) {
            int col = nt * 16 + ln;
            float bv = eb2[col];
            #pragma unroll
            for (int rt = 0; rt < 2; ++rt) {
                #pragma unroll
                for (int r = 0; r < 4; ++r)
                    mi[(w * 32 + rt * 16 + quad * 4 + r) * MIS + 128 + col] =
                        f2bf(ea[rt][nt][r] + bv);
            }
        }
    }

    // ---- A fragments ----
    short8 aA[5], aB[5];
    #pragma unroll
    for (int kc = 0; kc < 5; ++kc) {
        aA[kc] = *(const short8*)&mi[arow0 + kc * 32 + koff];
        aB[kc] = *(const short8*)&mi[arow1 + kc * 32 + koff];
    }

    const int wvoff = ln * 160 + koff;

    // ---- GEMM1-coord ----
    f32x4 accC[2][8];
    #pragma unroll
    for (int a = 0; a < 2; ++a)
        #pragma unroll
        for (int b = 0; b < 8; ++b) accC[a][b] = zero;
    {
        const unsigned short* wsrc = ws + 20480;
        #pragma unroll
        for (int half = 0; half < 2; ++half) {
            #pragma unroll
            for (int kc = 0; kc < 5; ++kc) {
                #pragma unroll
                for (int nt = 0; nt < 4; ++nt) {
                    short8 b = *(const short8*)(wsrc + half * 10240 + nt * 2560
                                                + kc * 32 + wvoff);
                    const int nn = half * 4 + nt;
                    accC[0][nn] = __builtin_amdgcn_mfma_f32_16x16x32_bf16(aA[kc], b, accC[0][nn], 0, 0, 0);
                    accC[1][nn] = __builtin_amdgcn_mfma_f32_16x16x32_bf16(aB[kc], b, accC[1][nn], 0, 0, 0);
                }
            }
        }
    }

    // ---- coord epilogue -> xacc (no atomics here) ----
    {
        float cw[2][4];
        #pragma unroll
        for (int mt = 0; mt < 2; ++mt)
            #pragma unroll
            for (int r = 0; r < 4; ++r) cw[mt][r] = 0.f;
        #pragma unroll
        for (int nt = 0; nt < 8; ++nt) {
            int col = nt * 16 + ln;
            float b1v = coord_b1[col];
            float w2v = coord_w2[col];
            #pragma unroll
            for (int mt = 0; mt < 2; ++mt)
                #pragma unroll
                for (int r = 0; r < 4; ++r)
                    cw[mt][r] += silu_f(accC[mt][nt][r] + b1v) * w2v;
        }
        #pragma unroll
        for (int off = 1; off < 16; off <<= 1) {
            #pragma unroll
            for (int mt = 0; mt < 2; ++mt)
                #pragma unroll
                for (int r = 0; r < 4; ++r)
                    cw[mt][r] += __shfl_xor(cw[mt][r], off, 64);
        }
        if (ln < 8) {
            const int smt = ln >> 2, sr = ln & 3;
            float cwsel = 0.f;
            #pragma unroll
            for (int mt = 0; mt < 2; ++mt)
                #pragma unroll
                for (int r = 0; r < 4; ++r)
                    cwsel = (mt == smt && r == sr) ? cw[mt][r] : cwsel;
            int lrow = w * 32 + smt * 16 + quad * 4 + sr;
            int s = srcS[lrow], dn = dstS[lrow];
            float dx, dy, dz;
            if (xp) {
                float4 xs = xp[s], xd = xp[dn];
                dx = xs.x - xd.x; dy = xs.y - xd.y; dz = xs.z - xd.z;
            } else {
                dx = x[s * 3]     - x[dn * 3];
                dy = x[s * 3 + 1] - x[dn * 3 + 1];
                dz = x[s * 3 + 2] - x[dn * 3 + 2];
            }
            float len = fmaxf(sqrtf(dx * dx + dy * dy + dz * dz), 1e-8f);
            float k = cwsel * __builtin_amdgcn_rcpf(len);
            xacc[lrow][0] = k * dx;
            xacc[lrow][1] = k * dy;
            xacc[lrow][2] = k * dz;
        }
    }

    // ---- GEMM1-node ----
    f32x4 accN[2][8];
    #pragma unroll
    for (int a = 0; a < 2; ++a)
        #pragma unroll
        for (int b = 0; b < 8; ++b) accN[a][b] = zero;
    {
        const unsigned short* wsrc = ws;
        #pragma unroll
        for (int half = 0; half < 2; ++half) {
            #pragma unroll
            for (int kc = 0; kc < 5; ++kc) {
                #pragma unroll
                for (int nt = 0; nt < 4; ++nt) {
                    short8 b = *(const short8*)(wsrc + half * 10240 + nt * 2560
                                                + kc * 32 + wvoff);
                    const int nn = half * 4 + nt;
                    accN[0][nn] = __builtin_amdgcn_mfma_f32_16x16x32_bf16(aA[kc], b, accN[0][nn], 0, 0, 0);
                    accN[1][nn] = __builtin_amdgcn_mfma_f32_16x16x32_bf16(aB[kc], b, accN[1][nn], 0, 0, 0);
                }
            }
        }
    }

    // ---- hidden = silu(accN + b1) -> bf16, own rows ----
    #pragma unroll
    for (int mt = 0; mt < 2; ++mt) {
        const int rowb = (w * 32 + mt * 16 + quad * 4) * MIS;
        #pragma unroll
        for (int nt = 0; nt < 8; ++nt) {
            int col = nt * 16 + ln;
            float b1v = node_b1[col];
            #pragma unroll
            for (int r = 0; r < 4; ++r)
                mi[rowb + r * MIS + col] = f2bf(silu_f(accN[mt][nt][r] + b1v));
        }
    }

    // ---- GEMM2-node ----
    f32x4 acc2[2][4];
    #pragma unroll
    for (int a = 0; a < 2; ++a)
        #pragma unroll
        for (int b = 0; b < 4; ++b) acc2[a][b] = zero;
    const unsigned short* nw2T = ws + 40960;
    #pragma unroll
    for (int kc = 0; kc < 4; ++kc) {
        short8 a0 = *(const short8*)&mi[arow0 + kc * 32 + koff];
        short8 a1 = *(const short8*)&mi[arow1 + kc * 32 + koff];
        #pragma unroll
        for (int nt = 0; nt < 4; ++nt) {
            short8 b = *(const short8*)(nw2T + (nt * 16 + ln) * 128 + kc * 32 + koff);
            acc2[0][nt] = __builtin_amdgcn_mfma_f32_16x16x32_bf16(a0, b, acc2[0][nt], 0, 0, 0);
            acc2[1][nt] = __builtin_amdgcn_mfma_f32_16x16x32_bf16(a1, b, acc2[1][nt], 0, 0, 0);
        }
    }

    // ---- m+b2 rows -> LDS fp32 ----
    // RACE FIX (round-7 NaN post-mortem): all waves' GEMM2 LDS reads must complete
    // before ANY wave's fp32 overwrite of mi. MAS=84 additionally keeps row lrow's
    // fp32 bytes inside mi row lrow, so writes stay in own-wave rows by construction.
    __syncthreads();
    float* macc = (float*)mi;   // [128][MAS]
    #pragma unroll
    for (int mt = 0; mt < 2; ++mt) {
        #pragma unroll
        for (int r = 0; r < 4; ++r) {
            int lrow = w * 32 + mt * 16 + quad * 4 + r;
            #pragma unroll
            for (int nt = 0; nt < 4; ++nt) {
                int col = nt * 16 + ln;
                macc[lrow * MAS + col] = acc2[mt][nt][r] + node_b2[col];
            }
        }
    }
    __syncthreads();   // macc + xacc visible to all

    // ---- segmented reduce: thread = (col, row-quarter); wave-uniform branches ----
    {
        const int col = tid & 63;
        const int q   = tid >> 6;
        const int r0  = q * 32;
        float sum = 0.f;
        int prev = dstS[r0];
        for (int r = r0; r < r0 + 32; ++r) {
            int d = dstS[r];
            if (d != prev) {
                atomicAdd(out_h + (size_t)prev * 64 + col, sum);
                sum = 0.f; prev = d;
            }
            sum += macc[r * MAS + col];
        }
        atomicAdd(out_h + (size_t)prev * 64 + col, sum);

        if (col < 3) {
            float xs = 0.f;
            int pv = dstS[r0];
            for (int r = r0; r < r0 + 32; ++r) {
                int d = dstS[r];
                if (d != pv) {
                    atomicAdd(out_x + pv * 3 + col, xs);
                    xs = 0.f; pv = d;
                }
                xs += xacc[r][col];
            }
            atomicAdd(out_x + pv * 3 + col, xs);
        }
    }
}

// ================= fallback: round-5 kernel (per-edge atomics), verbatim =================
__global__ __launch_bounds__(256, 3)
void egnn_edge_kernel(const float* __restrict__ h,
                      const unsigned short* __restrict__ hb,
                      const float* __restrict__ x,
                      const float4* __restrict__ xp,
                      const int* __restrict__ eidx,
                      const float* __restrict__ edist,
                      const float* __restrict__ node_b1,
                      const float* __restrict__ node_b2,
                      const float* __restrict__ coord_b1,
                      const float* __restrict__ coord_w2,
                      const float* __restrict__ ew1,
                      const float* __restrict__ eb1,
                      const float* __restrict__ eb2,
                      const unsigned short* __restrict__ ws,
                      float* __restrict__ out_h,
                      float* __restrict__ out_x) {
    __shared__ unsigned short mi[BE * MIS];
    __shared__ int srcS[BE];
    __shared__ int dstS[BE];

    const int tid  = threadIdx.x;
    const int w    = tid >> 6;
    const int lane = tid & 63;
    const int ln   = lane & 15;
    const int quad = lane >> 4;
    const int e0   = blockIdx.x * BE;

    if (tid < BE)      srcS[tid]       = eidx[e0 + tid];
    else               dstS[tid - BE]  = eidx[NE + e0 + tid - BE];
    __syncthreads();

    if (hb) {
        const uint2* hb2 = (const uint2*)hb;
        const int g = tid >> 4, l16 = tid & 15;
        #pragma unroll
        for (int it = 0; it < 16; ++it) {
            int row = it * 16 + g;
            int e = row & 127;
            int node = (row < 128) ? srcS[e] : dstS[e];
            int cbase = (row < 128) ? 0 : 64;
            *(uint2*)&mi[e * MIS + cbase + l16 * 4] = hb2[node * 16 + l16];
        }
    } else {
        const float4* h4 = (const float4*)h;
        const int g = tid >> 4, l16 = tid & 15;
        #pragma unroll
        for (int it = 0; it < 16; ++it) {
            int row = it * 16 + g;
            int e = row & 127;
            int node = (row < 128) ? srcS[e] : dstS[e];
            int cbase = (row < 128) ? 0 : 64;
            float4 v = h4[node * 16 + l16];
            uint2 u;
            u.x = pk2bf(v.x, v.y);
            u.y = pk2bf(v.z, v.w);
            *(uint2*)&mi[e * MIS + cbase + l16 * 4] = u;
        }
    }
    {
        int e = tid >> 1, half = tid & 1;
        float d = edist[e0 + e];
        float t[16];
        #pragma unroll
        for (int j = 0; j < 16; ++j) {
            int k = half * 16 + j;
            t[j] = silu_f(d * ew1[k] + eb1[k]);
        }
        uint4 u0, u1;
        u0.x = pk2bf(t[0], t[1]);   u0.y = pk2bf(t[2], t[3]);
        u0.z = pk2bf(t[4], t[5]);   u0.w = pk2bf(t[6], t[7]);
        u1.x = pk2bf(t[8], t[9]);   u1.y = pk2bf(t[10], t[11]);
        u1.z = pk2bf(t[12], t[13]); u1.w = pk2bf(t[14], t[15]);
        *(uint4*)&mi[e * MIS + 128 + half * 16]     = u0;
        *(uint4*)&mi[e * MIS + 128 + half * 16 + 8] = u1;
    }

    __syncthreads();

    const int arow0 = (w * 32 + ln) * MIS;
    const int arow1 = (w * 32 + 16 + ln) * MIS;
    const int koff  = quad * 8;
    const f32x4 zero = {0.f, 0.f, 0.f, 0.f};

    {
        const unsigned short* e2T = ws + WS_EW2T_US;
        short8 ta0 = *(const short8*)&mi[arow0 + 128 + koff];
        short8 ta1 = *(const short8*)&mi[arow1 + 128 + koff];
        f32x4 ea[2][2];
        ea[0][0] = zero; ea[0][1] = zero; ea[1][0] = zero; ea[1][1] = zero;
        #pragma unroll
        for (int nt = 0; nt < 2; ++nt) {
            short8 b = *(const short8*)(e2T + (nt * 16 + ln) * 32 + koff);
            ea[0][nt] = __builtin_amdgcn_mfma_f32_16x16x32_bf16(ta0, b, ea[0][nt], 0, 0, 0);
            ea[1][nt] = __builtin_amdgcn_mfma_f32_16x16x32_bf16(ta1, b, ea[1][nt], 0, 0, 0);
        }
        #pragma unroll
        for (int nt = 0; nt < 2; ++nt) {
            int col = nt * 16 + ln;
            float bv = eb2[col];
            #pragma unroll
            for (int rt = 0; rt < 2; ++rt) {
                #pragma unroll
                for (int r = 0; r < 4; ++r)
                    mi[(w * 32 + rt * 16 + quad * 4 + r) * MIS + 128 + col] =
                        f2bf(ea[rt][nt][r] + bv);
            }
        }
    }

    short8 aA[5], aB[5];
    #pragma unroll
    for (int kc = 0; kc < 5; ++kc) {
        aA[kc] = *(const short8*)&mi[arow0 + kc * 32 + koff];
        aB[kc] = *(const short8*)&mi[arow1 + kc * 32 + koff];
    }

    const int wvoff = ln * 160 + koff;

    f32x4 accC[2][8];
    #pragma unroll
    for (int a = 0; a < 2; ++a)
        #pragma unroll
        for (int b = 0; b < 8; ++b) accC[a][b] = zero;
    {
        const unsigned short* wsrc = ws + 20480;
        #pragma unroll
        for (int half = 0; half < 2; ++half) {
            #pragma unroll
            for (int kc = 0; kc < 5; ++kc) {
                #pragma unroll
                for (int nt = 0; nt < 4; ++nt) {
                    short8 b = *(const short8*)(wsrc + half * 10240 + nt * 2560
                                                + kc * 32 + wvoff);
                    const int nn = half * 4 + nt;
                    accC[0][nn] = __builtin_amdgcn_mfma_f32_16x16x32_bf16(aA[kc], b, accC[0][nn], 0, 0, 0);
                    accC[1][nn] = __builtin_amdgcn_mfma_f32_16x16x32_bf16(aB[kc], b, accC[1][nn], 0, 0, 0);
                }
            }
        }
    }

    {
        float cw[2][4];
        #pragma unroll
        for (int mt = 0; mt < 2; ++mt)
            #pragma unroll
            for (int r = 0; r < 4; ++r) cw[mt][r] = 0.f;
        #pragma unroll
        for (int nt = 0; nt < 8; ++nt) {
            int col = nt * 16 + ln;
            float b1v = coord_b1[col];
            float w2v = coord_w2[col];
            #pragma unroll
            for (int mt = 0; mt < 2; ++mt)
                #pragma unroll
                for (int r = 0; r < 4; ++r)
                    cw[mt][r] += silu_f(accC[mt][nt][r] + b1v) * w2v;
        }
        #pragma unroll
        for (int off = 1; off < 16; off <<= 1) {
            #pragma unroll
            for (int mt = 0; mt < 2; ++mt)
                #pragma unroll
                for (int r = 0; r < 4; ++r)
                    cw[mt][r] += __shfl_xor(cw[mt][r], off, 64);
        }
        if (ln < 8) {
            const int smt = ln >> 2, sr = ln & 3;
            float cwsel = 0.f;
            #pragma unroll
            for (int mt = 0; mt < 2; ++mt)
                #pragma unroll
                for (int r = 0; r < 4; ++r)
                    cwsel = (mt == smt && r == sr) ? cw[mt][r] : cwsel;
            int lrow = w * 32 + smt * 16 + quad * 4 + sr;
            int s = srcS[lrow], dn = dstS[lrow];
            float dx, dy, dz;
            if (xp) {
                float4 xs = xp[s], xd = xp[dn];
                dx = xs.x - xd.x; dy = xs.y - xd.y; dz = xs.z - xd.z;
            } else {
                dx = x[s * 3]     - x[dn * 3];
                dy = x[s * 3 + 1] - x[dn * 3 + 1];
                dz = x[s * 3 + 2] - x[dn * 3 + 2];
            }
            float len = fmaxf(sqrtf(dx * dx + dy * dy + dz * dz), 1e-8f);
            float k = cwsel * __builtin_amdgcn_rcpf(len);
            atomicAdd(out_x + dn * 3,     k * dx);
            atomicAdd(out_x + dn * 3 + 1, k * dy);
            atomicAdd(out_x + dn * 3 + 2, k * dz);
        }
    }

    f32x4 accN[2][8];
    #pragma unroll
    for (int a = 0; a < 2; ++a)
        #pragma unroll
        for (int b = 0; b < 8; ++b) accN[a][b] = zero;
    {
        const unsigned short* wsrc = ws;
        #pragma unroll
        for (int half = 0; half < 2; ++half) {
            #pragma unroll
            for (int kc = 0; kc < 5; ++kc) {
                #pragma unroll
                for (int nt = 0; nt < 4; ++nt) {
                    short8 b = *(const short8*)(wsrc + half * 10240 + nt * 2560
                                                + kc * 32 + wvoff);
                    const int nn = half * 4 + nt;
                    accN[0][nn] = __builtin_amdgcn_mfma_f32_16x16x32_bf16(aA[kc], b, accN[0][nn], 0, 0, 0);
                    accN[1][nn] = __builtin_amdgcn_mfma_f32_16x16x32_bf16(aB[kc], b, accN[1][nn], 0, 0, 0);
                }
            }
        }
    }

    #pragma unroll
    for (int mt = 0; mt < 2; ++mt) {
        const int rowb = (w * 32 + mt * 16 + quad * 4) * MIS;
        #pragma unroll
        for (int nt = 0; nt < 8; ++nt) {
            int col = nt * 16 + ln;
            float b1v = node_b1[col];
            #pragma unroll
            for (int r = 0; r < 4; ++r)
                mi[rowb + r * MIS + col] = f2bf(silu_f(accN[mt][nt][r] + b1v));
        }
    }

    f32x4 acc2[2][4];
    #pragma unroll
    for (int a = 0; a < 2; ++a)
        #pragma unroll
        for (int b = 0; b < 4; ++b) acc2[a][b] = zero;
    const unsigned short* nw2T = ws + 40960;
    #pragma unroll
    for (int kc = 0; kc < 4; ++kc) {
        short8 a0 = *(const short8*)&mi[arow0 + kc * 32 + koff];
        short8 a1 = *(const short8*)&mi[arow1 + kc * 32 + koff];
        #pragma unroll
        for (int nt = 0; nt < 4; ++nt) {
            short8 b = *(const short8*)(nw2T + (nt * 16 + ln) * 128 + kc * 32 + koff);
            acc2[0][nt] = __builtin_amdgcn_mfma_f32_16x16x32_bf16(a0, b, acc2[0][nt], 0, 0, 0);
            acc2[1][nt] = __builtin_amdgcn_mfma_f32_16x16x32_bf16(a1, b, acc2[1][nt], 0, 0, 0);
        }
    }
    #pragma unroll
    for (int mt = 0; mt < 2; ++mt) {
        #pragma unroll
        for (int r = 0; r < 4; ++r) {
            int lrow = w * 32 + mt * 16 + quad * 4 + r;
            int dn = dstS[lrow];
            float* outrow = out_h + (size_t)dn * 64;
            #pragma unroll
            for (int nt = 0; nt < 4; ++nt) {
                int col = nt * 16 + ln;
                atomicAdd(outrow + col, acc2[mt][nt][r] + node_b2[col]);
            }
        }
    }
}

extern "C" void kernel_launch(void* const* d_in, const int* in_sizes, int n_in,
                              void* d_out, int out_size, void* d_ws, size_t ws_size,
                              hipStream_t stream) {
    const float* h    = (const float*)d_in[0];
    const float* x    = (const float*)d_in[1];
    const int*   eidx = (const int*)d_in[2];
    const float* edist= (const float*)d_in[3];
    const float* nw1  = (const float*)d_in[4];
    const float* nb1  = (const float*)d_in[5];
    const float* nw2  = (const float*)d_in[6];
    const float* nb2  = (const float*)d_in[7];
    const float* cw1  = (const float*)d_in[8];
    const float* cb1  = (const float*)d_in[9];
    const float* cw2  = (const float*)d_in[10];
    const float* ew1  = (const float*)d_in[11];
    const float* eb1  = (const float*)d_in[12];
    const float* ew2  = (const float*)d_in[13];
    const float* eb2  = (const float*)d_in[14];
    float* out = (float*)d_out;
    unsigned short* ws = (unsigned short*)d_ws;

    unsigned short* hb = nullptr;
    float4* xp = nullptr;
    if (ws_size >= (size_t)WS_HB_NEED) hb = (unsigned short*)((char*)d_ws + WS_HB_B);
    if (ws_size >= (size_t)WS_XP_NEED) xp = (float4*)((char*)d_ws + WS_XP_B);

    prep_kernel<<<196, 256, 0, stream>>>(nw1, cw1, nw2, ew2, ws);
    fused_init<<<3468, 256, 0, stream>>>((const float4*)h, x, (const float4*)x,
                                         (float4*)out, hb, xp);

    if (ws_size >= (size_t)WS_SORT_NEED) {
        int*   hist   = (int*)((char*)d_ws + WS_HIST_B);
        int*   sums   = hist + 50000;            // 49 chunk sums in hist padding
        int*   src_s  = (int*)((char*)d_ws + WS_SRC_B);
        int*   dst_s  = (int*)((char*)d_ws + WS_DST_B);
        float* dist_s = (float*)((char*)d_ws + WS_DIST_B);
        zero_hist<<<196, 256, 0, stream>>>(hist);
        hist_kernel<<<NE / 256, 256, 0, stream>>>(eidx, hist);
        scan_part<<<49, 1024, 0, stream>>>(hist, sums);
        scan_sums<<<1, 64, 0, stream>>>(sums);
        scan_add<<<49, 1024, 0, stream>>>(hist, sums);
        scatter_kernel<<<NE / 256, 256, 0, stream>>>(eidx, edist, hist,
                                                     src_s, dst_s, dist_s);
        egnn_edge_sorted<<<NE / BE, 256, 0, stream>>>(h, hb, x, xp,
                                                      src_s, dst_s, dist_s,
                                                      nb1, nb2, cb1, cw2,
                                                      ew1, eb1, eb2,
                                                      ws, out, out + 3200000);
    } else {
        egnn_edge_kernel<<<NE / BE, 256, 0, stream>>>(h, hb, x, xp, eidx, edist,
                                                      nb1, nb2, cb1, cw2,
                                                      ew1, eb1, eb2,
                                                      ws, out, out + 3200000);
    }
}